// Round 11
// baseline (336.167 us; speedup 1.0000x reference)
//
#include <hip/hip_runtime.h>
#include <hip/hip_fp16.h>

#define GNUM 128
#define HEADS 4
#define FEAT 64
#define CH 256      // HEADS*FEAT
#define LAT 256
#define SLOPE 0.2f
#define CAP 64      // max in-degree capacity (verified: max deg <= 64)
#define POSMAX 180  // one-hot position classes upper bound

typedef _Float16 h16;
typedef __attribute__((ext_vector_type(4))) _Float16 half4;
typedef __attribute__((ext_vector_type(8))) _Float16 half8;
typedef __attribute__((ext_vector_type(4))) float floatx4;

__device__ __forceinline__ float lrelu(float x) { return fmaxf(x, SLOPE * x); }

// ---- merged setup: [blocks 0..575] cnt=0 + starts + weight fp16 conversion;
//      [576..703] per-graph A row + graph logit table; [704..883] position logit table. ----
__global__ __launch_bounds__(256) void k_setup(const int* __restrict__ batch, int* __restrict__ cnt,
                                               int* __restrict__ starts, int n,
                                               const float* __restrict__ W2, const float* __restrict__ W3,
                                               const float* __restrict__ Wg, h16* __restrict__ W2T,
                                               h16* __restrict__ W3T, h16* __restrict__ WgT,
                                               const float* __restrict__ z, const float* __restrict__ W0,
                                               const float* __restrict__ b0, const float* __restrict__ W1,
                                               const float* __restrict__ as1, const float* __restrict__ ad1,
                                               float* __restrict__ A, float* __restrict__ asg,
                                               float* __restrict__ adg, float* __restrict__ asp,
                                               float* __restrict__ adp) {
  __shared__ float red[4][FEAT];
  __shared__ float xzs[FEAT];
  int bx = blockIdx.x, t = threadIdx.x;
  if (bx < 576) {
    int idx = bx * 256 + t;
    if (idx < n) {
      cnt[idx] = 0;
      int b = batch[idx];
      if (idx == 0 || batch[idx - 1] != b) starts[b] = idx;
    }
    if (idx < 65536) {
      int kb = idx >> 13, rem = idx & 8191, j = rem >> 8, nn = rem & 255;
      W2T[kb * 8192 + nn * 32 + j] = (h16)W2[(kb * 32 + j) * 256 + nn];
    } else if (idx < 131072) {
      int l = idx - 65536;
      int kb = l >> 13, rem = l & 8191, j = rem >> 8, nn = rem & 255;
      W3T[kb * 8192 + nn * 32 + j] = (h16)W3[(kb * 32 + j) * 256 + nn];
    } else {
      int l = idx - 131072;
      int kb = l >> 11, rem = l & 2047, j = rem >> 6, nn = rem & 63;
      WgT[kb * 2048 + nn * 32 + j] = (h16)Wg[(kb * 32 + j) * 64 + nn];
    }
  } else if (bx < 576 + GNUM) {
    int g = bx - 576;
    int f = t & 63, kq = t >> 6;
    float acc = 0.f;
    for (int k = kq * 64; k < kq * 64 + 64; ++k) acc += z[g * LAT + k] * W0[k * FEAT + f];
    red[kq][f] = acc;
    __syncthreads();
    if (kq == 0)
      xzs[f] = fmaxf(red[0][f] + red[1][f] + red[2][f] + red[3][f] + b0[f], 0.f);
    __syncthreads();
    float a2 = 0.f;
#pragma unroll 16
    for (int k = 0; k < FEAT; ++k) a2 += xzs[k] * W1[k * CH + t];
    A[g * CH + t] = a2;
    float ps = a2 * as1[t], pd = a2 * ad1[t];
#pragma unroll
    for (int sh = 1; sh < 64; sh <<= 1) {
      ps += __shfl_xor(ps, sh, 64);
      pd += __shfl_xor(pd, sh, 64);
    }
    if ((t & 63) == 0) {
      asg[g * 4 + (t >> 6)] = ps;
      adg[g * 4 + (t >> 6)] = pd;
    }
  } else {
    int p = bx - (576 + GNUM);
    float wv = W1[(size_t)(FEAT + p) * CH + t];
    float ps = wv * as1[t], pd = wv * ad1[t];
#pragma unroll
    for (int sh = 1; sh < 64; sh <<= 1) {
      ps += __shfl_xor(ps, sh, 64);
      pd += __shfl_xor(pd, sh, 64);
    }
    if ((t & 63) == 0) {
      asp[p * 4 + (t >> 6)] = ps;
      adp[p * 4 + (t >> 6)] = pd;
    }
  }
}

// ---- fused H1 materialization + logit tables [blocks 0..N/8) + edge scatter [rest]. ----
__global__ __launch_bounds__(256) void k_pre(const float* __restrict__ A, const float* __restrict__ W1,
                                             const int* __restrict__ batch, const int* __restrict__ starts,
                                             const float* __restrict__ asg, const float* __restrict__ adg,
                                             const float* __restrict__ asp, const float* __restrict__ adp,
                                             h16* __restrict__ H16, float* __restrict__ a_s,
                                             float* __restrict__ a_d, int n,
                                             const int* __restrict__ src, const int* __restrict__ dst,
                                             int* __restrict__ cnt, int* __restrict__ bucket, int e,
                                             int h1blocks) {
  int t = threadIdx.x;
  if ((int)blockIdx.x < h1blocks) {
    int row = blockIdx.x * 8 + (t >> 5);
    if (row < n) {
      int g = batch[row];
      int p = row - starts[g];
      int c0 = (t & 31) * 8;
      const float* ap = A + g * CH + c0;
      const float* wp = W1 + (size_t)(FEAT + p) * CH + c0;
      float4 a0 = *(const float4*)ap;
      float4 a1 = *(const float4*)(ap + 4);
      float4 w0v = *(const float4*)wp;
      float4 w1v = *(const float4*)(wp + 4);
      half8 o;
      o[0] = (h16)(a0.x + w0v.x); o[1] = (h16)(a0.y + w0v.y);
      o[2] = (h16)(a0.z + w0v.z); o[3] = (h16)(a0.w + w0v.w);
      o[4] = (h16)(a1.x + w1v.x); o[5] = (h16)(a1.y + w1v.y);
      o[6] = (h16)(a1.z + w1v.z); o[7] = (h16)(a1.w + w1v.w);
      *(half8*)(H16 + (size_t)row * CH + c0) = o;
    }
    int idx = blockIdx.x * 256 + t;
    if (idx < n * 4) {
      int nn = idx >> 2, h = idx & 3;
      int g2 = batch[nn], p2 = nn - starts[g2];
      a_s[idx] = asg[g2 * 4 + h] + asp[p2 * 4 + h];
      a_d[idx] = adg[g2 * 4 + h] + adp[p2 * 4 + h];
    }
  } else {
    int i = (blockIdx.x - h1blocks) * 256 + t;
    if (i < e) {
      int d = dst[i];
      int p = atomicAdd(&cnt[d], 1);
      if (p < CAP) bucket[d * CAP + p] = src[i];
    }
  }
}

// ======= fused layer v2: 1024-thread block = 16 waves; 64 nodes/block (4 per wave,
//   serial, per-wave private LDS slots, NO barrier in loop -> straggler averaged over
//   4 nodes: max-of-16-sums ~1.15x mean vs 1.85x at 1 node/wave in R10).
// Phase B: 64x256 MFMA tile (grid 300 -> 4x less redundant B traffic than R10);
//   wave = (row-block rb, 64-col head strip cs); logits complete in-wave.
// X never round-trips through global. H/a ping-pong across layers. =======
__global__ __launch_bounds__(1024) void k_fgg(const h16* __restrict__ H16i, const float* __restrict__ a_si,
                                              const float* __restrict__ a_di, const float* __restrict__ bias,
                                              const int* __restrict__ cnt, const int* __restrict__ bucket,
                                              const h16* __restrict__ WT, const float* __restrict__ att_s,
                                              const float* __restrict__ att_d, h16* __restrict__ H16o,
                                              float* __restrict__ a_so, float* __restrict__ a_do_) {
  __shared__ __align__(16) char smemc[54272];
  h16* Xs = (h16*)smemc;                     // 64*264*2 = 33792 B
  float* wsh = (float*)(smemc + 33792);      // [16][CAP][4] = 16384 B
  int* bsh = (int*)(smemc + 50176);          // [16][CAP] = 4096 B
  int t = threadIdx.x, wv = t >> 6, lane = t & 63;
  int quad = lane >> 4, l15 = lane & 15;
  int row0 = blockIdx.x * 64;
  int hh = lane >> 4, fo = lane * 4;
  // ---- Phase A: gather, 4 nodes per wave (R3-proven body, no barriers) ----
  for (int i = 0; i < 4; ++i) {
    int n = row0 + wv * 4 + i;
    int c = min(cnt[n], CAP);
    bool valid = lane < c;
    int sc = valid ? bucket[n * CAP + lane] : n;
    if (valid) bsh[wv * CAP + lane] = sc;
    float4 ea4 = *(const float4*)(a_si + (size_t)sc * 4);
    float4 sn4 = *(const float4*)(a_si + (size_t)n * 4);
    float4 dn4 = *(const float4*)(a_di + (size_t)n * 4);
    float ea[4] = {ea4.x, ea4.y, ea4.z, ea4.w};
    float sn[4] = {sn4.x, sn4.y, sn4.z, sn4.w};
    float dn[4] = {dn4.x, dn4.y, dn4.z, dn4.w};
    float asf[4];
#pragma unroll
    for (int h = 0; h < 4; ++h) {
      float e = valid ? lrelu(ea[h] + dn[h]) : -1e30f;
      float es = lrelu(sn[h] + dn[h]);   // self loop logit
      float m = e;
#pragma unroll
      for (int sh = 1; sh < 64; sh <<= 1) m = fmaxf(m, __shfl_xor(m, sh, 64));
      m = fmaxf(m, es);
      float wgt = valid ? __expf(e - m) : 0.f;
      float ws = __expf(es - m);
      float s = wgt;
#pragma unroll
      for (int sh = 1; sh < 64; sh <<= 1) s += __shfl_xor(s, sh, 64);
      s += ws;
      float inv = 1.f / (s + 1e-16f);
      if (valid) wsh[(wv * CAP + lane) * 4 + h] = wgt * inv;
      asf[h] = ws * inv;
    }
    half4 hv = *(const half4*)(H16i + (size_t)n * CH + fo);
    float a_self = asf[hh];
    float acc0 = a_self * (float)hv[0];
    float acc1 = a_self * (float)hv[1];
    float acc2 = a_self * (float)hv[2];
    float acc3 = a_self * (float)hv[3];
#define GLD(k) (*(const half4*)(H16i + (size_t)bsh[wv * CAP + (k)] * CH + fo))
    half4 q0, q1, q2, q3, q4, q5, q6, q7;
    if (c > 0) q0 = GLD(0);
    if (c > 1) q1 = GLD(1);
    if (c > 2) q2 = GLD(2);
    if (c > 3) q3 = GLD(3);
    if (c > 4) q4 = GLD(4);
    if (c > 5) q5 = GLD(5);
    if (c > 6) q6 = GLD(6);
    if (c > 7) q7 = GLD(7);
    for (int j0 = 0; j0 < c; j0 += 8) {
#define STEP(K, QK)                                              \
      if (j0 + K < c) {                                          \
        float wj = wsh[(wv * CAP + j0 + K) * 4 + hh];            \
        half4 hc = QK;                                           \
        if (j0 + K + 8 < c) QK = GLD(j0 + K + 8);                \
        acc0 += wj * (float)hc[0];                               \
        acc1 += wj * (float)hc[1];                               \
        acc2 += wj * (float)hc[2];                               \
        acc3 += wj * (float)hc[3];                               \
      }
      STEP(0, q0) STEP(1, q1) STEP(2, q2) STEP(3, q3)
      STEP(4, q4) STEP(5, q5) STEP(6, q6) STEP(7, q7)
#undef STEP
    }
#undef GLD
    float4 b4 = *(const float4*)(bias + fo);
    half4 o;
    o[0] = (h16)fmaxf(acc0 + b4.x, 0.f);
    o[1] = (h16)fmaxf(acc1 + b4.y, 0.f);
    o[2] = (h16)fmaxf(acc2 + b4.z, 0.f);
    o[3] = (h16)fmaxf(acc3 + b4.w, 0.f);
    *(half4*)&Xs[(wv * 4 + i) * 264 + fo] = o;
  }
  __syncthreads();   // X tile complete
  // ---- Phase B: 64x256 GEMM; wave = (rb = wv>>2 row-block, cs = wv&3 head strip) ----
  int rb = wv >> 2, cs = wv & 3;
  floatx4 acc[4];
#pragma unroll
  for (int nt = 0; nt < 4; ++nt) acc[nt] = (floatx4){0.f, 0.f, 0.f, 0.f};
#pragma unroll
  for (int kb = 0; kb < 8; ++kb) {
    half8 af = *(const half8*)&Xs[(rb * 16 + l15) * 264 + kb * 32 + quad * 8];
    const h16* bp = WT + kb * 8192 + (cs * 64 + l15) * 32 + quad * 8;
    half8 b0 = *(const half8*)(bp + 0 * 512);
    half8 b1 = *(const half8*)(bp + 1 * 512);
    half8 b2 = *(const half8*)(bp + 2 * 512);
    half8 b3 = *(const half8*)(bp + 3 * 512);
    acc[0] = __builtin_amdgcn_mfma_f32_16x16x32_f16(af, b0, acc[0], 0, 0, 0);
    acc[1] = __builtin_amdgcn_mfma_f32_16x16x32_f16(af, b1, acc[1], 0, 0, 0);
    acc[2] = __builtin_amdgcn_mfma_f32_16x16x32_f16(af, b2, acc[2], 0, 0, 0);
    acc[3] = __builtin_amdgcn_mfma_f32_16x16x32_f16(af, b3, acc[3], 0, 0, 0);
  }
  // fused logits: strip cs == head cs; complete in-wave (R0-proven pattern)
  {
    float asv[4], adv[4];
#pragma unroll
    for (int nt = 0; nt < 4; ++nt) {
      asv[nt] = att_s[cs * FEAT + nt * 16 + l15];
      adv[nt] = att_d[cs * FEAT + nt * 16 + l15];
    }
#pragma unroll
    for (int r = 0; r < 4; ++r) {
      float ps = acc[0][r] * asv[0] + acc[1][r] * asv[1] +
                 acc[2][r] * asv[2] + acc[3][r] * asv[3];
      float pd = acc[0][r] * adv[0] + acc[1][r] * adv[1] +
                 acc[2][r] * adv[2] + acc[3][r] * adv[3];
#pragma unroll
      for (int sh = 1; sh < 16; sh <<= 1) {
        ps += __shfl_xor(ps, sh, 16);
        pd += __shfl_xor(pd, sh, 16);
      }
      if (l15 == 0) {
        int row = row0 + rb * 16 + quad * 4 + r;
        a_so[(size_t)row * 4 + cs] = ps;
        a_do_[(size_t)row * 4 + cs] = pd;
      }
    }
  }
  __syncthreads();   // all Xs (af) reads done -> safe to overwrite with H tile
#pragma unroll
  for (int nt = 0; nt < 4; ++nt)
#pragma unroll
    for (int r = 0; r < 4; ++r)
      Xs[(rb * 16 + quad * 4 + r) * 264 + cs * 64 + nt * 16 + l15] = (h16)acc[nt][r];
  __syncthreads();
  // H-tile to global (coalesced)
  {
    int row = t >> 4, seg = t & 15;
    const h16* srcr = &Xs[row * 264 + seg * 16];
    h16* dstr = H16o + (size_t)(row0 + row) * CH + seg * 16;
    *(half8*)(dstr + 0) = *(const half8*)(srcr + 0);
    *(half8*)(dstr + 8) = *(const half8*)(srcr + 8);
  }
}

// ======= fused last layer v2: gather (64 nodes/block) + head =======
__global__ __launch_bounds__(1024) void k_fgh(const h16* __restrict__ H16i, const float* __restrict__ a_si,
                                              const float* __restrict__ a_di, const float* __restrict__ bias,
                                              const int* __restrict__ cnt, const int* __restrict__ bucket,
                                              const h16* __restrict__ WgT, const float* __restrict__ bg,
                                              const float* __restrict__ Wf, const float* __restrict__ bfv,
                                              float* __restrict__ out) {
  __shared__ __align__(16) char smemc[55552];
  h16* Xs = (h16*)smemc;                     // 33792 B
  float* wsh = (float*)(smemc + 33792);      // 16384 B (aliased by ytile after phase A)
  int* bsh = (int*)(smemc + 50176);          // 4096 B
  float* WfS = (float*)(smemc + 54272);      // 1280 B
  int t = threadIdx.x, wv = t >> 6, lane = t & 63;
  int quad = lane >> 4, l15 = lane & 15;
  int row0 = blockIdx.x * 64;
  int hh = lane >> 4, fo = lane * 4;
  if (t < FEAT * 5) WfS[t] = Wf[t];
  // ---- Phase A: gather, 4 nodes per wave ----
  for (int i = 0; i < 4; ++i) {
    int n = row0 + wv * 4 + i;
    int c = min(cnt[n], CAP);
    bool valid = lane < c;
    int sc = valid ? bucket[n * CAP + lane] : n;
    if (valid) bsh[wv * CAP + lane] = sc;
    float4 ea4 = *(const float4*)(a_si + (size_t)sc * 4);
    float4 sn4 = *(const float4*)(a_si + (size_t)n * 4);
    float4 dn4 = *(const float4*)(a_di + (size_t)n * 4);
    float ea[4] = {ea4.x, ea4.y, ea4.z, ea4.w};
    float sn[4] = {sn4.x, sn4.y, sn4.z, sn4.w};
    float dn[4] = {dn4.x, dn4.y, dn4.z, dn4.w};
    float asf[4];
#pragma unroll
    for (int h = 0; h < 4; ++h) {
      float e = valid ? lrelu(ea[h] + dn[h]) : -1e30f;
      float es = lrelu(sn[h] + dn[h]);
      float m = e;
#pragma unroll
      for (int sh = 1; sh < 64; sh <<= 1) m = fmaxf(m, __shfl_xor(m, sh, 64));
      m = fmaxf(m, es);
      float wgt = valid ? __expf(e - m) : 0.f;
      float ws = __expf(es - m);
      float s = wgt;
#pragma unroll
      for (int sh = 1; sh < 64; sh <<= 1) s += __shfl_xor(s, sh, 64);
      s += ws;
      float inv = 1.f / (s + 1e-16f);
      if (valid) wsh[(wv * CAP + lane) * 4 + h] = wgt * inv;
      asf[h] = ws * inv;
    }
    half4 hv = *(const half4*)(H16i + (size_t)n * CH + fo);
    float a_self = asf[hh];
    float acc0 = a_self * (float)hv[0];
    float acc1 = a_self * (float)hv[1];
    float acc2 = a_self * (float)hv[2];
    float acc3 = a_self * (float)hv[3];
#define GLD(k) (*(const half4*)(H16i + (size_t)bsh[wv * CAP + (k)] * CH + fo))
    half4 q0, q1, q2, q3, q4, q5, q6, q7;
    if (c > 0) q0 = GLD(0);
    if (c > 1) q1 = GLD(1);
    if (c > 2) q2 = GLD(2);
    if (c > 3) q3 = GLD(3);
    if (c > 4) q4 = GLD(4);
    if (c > 5) q5 = GLD(5);
    if (c > 6) q6 = GLD(6);
    if (c > 7) q7 = GLD(7);
    for (int j0 = 0; j0 < c; j0 += 8) {
#define STEP(K, QK)                                              \
      if (j0 + K < c) {                                          \
        float wj = wsh[(wv * CAP + j0 + K) * 4 + hh];            \
        half4 hc = QK;                                           \
        if (j0 + K + 8 < c) QK = GLD(j0 + K + 8);                \
        acc0 += wj * (float)hc[0];                               \
        acc1 += wj * (float)hc[1];                               \
        acc2 += wj * (float)hc[2];                               \
        acc3 += wj * (float)hc[3];                               \
      }
      STEP(0, q0) STEP(1, q1) STEP(2, q2) STEP(3, q3)
      STEP(4, q4) STEP(5, q5) STEP(6, q6) STEP(7, q7)
#undef STEP
    }
#undef GLD
    float4 b4 = *(const float4*)(bias + fo);
    half4 o;
    o[0] = (h16)fmaxf(acc0 + b4.x, 0.f);
    o[1] = (h16)fmaxf(acc1 + b4.y, 0.f);
    o[2] = (h16)fmaxf(acc2 + b4.z, 0.f);
    o[3] = (h16)fmaxf(acc3 + b4.w, 0.f);
    *(half4*)&Xs[(wv * 4 + i) * 264 + fo] = o;
  }
  __syncthreads();   // X tile + WfS complete; wsh reads done (ytile may alias)
  // ---- Phase B: head GEMM 64x64; wave = (rb = wv>>2 rows, cs = wv&3 col-16) ----
  int rb = wv >> 2, cs = wv & 3;
  floatx4 acc = (floatx4){0.f, 0.f, 0.f, 0.f};
#pragma unroll
  for (int kb = 0; kb < 8; ++kb) {
    half8 af = *(const half8*)&Xs[(rb * 16 + l15) * 264 + kb * 32 + quad * 8];
    half8 bf = *(const half8*)(WgT + kb * 2048 + (cs * 16 + l15) * 32 + quad * 8);
    acc = __builtin_amdgcn_mfma_f32_16x16x32_f16(af, bf, acc, 0, 0, 0);
  }
  float* ytile = (float*)(smemc + 33792);    // [64][68] fp32 = 17408 B (aliases wsh+bsh head)
  {
    int col = cs * 16 + l15;
    float bgv = bg[col];
#pragma unroll
    for (int r = 0; r < 4; ++r)
      ytile[(rb * 16 + quad * 4 + r) * 68 + col] = fmaxf(acc[r] + bgv, 0.f);
  }
  __syncthreads();
  if (t < 64 * 5) {
    int row = t / 5, o = t % 5;
    float s = bfv[o];
#pragma unroll
    for (int k = 0; k < FEAT; ++k) s += ytile[row * 68 + k] * WfS[k * 5 + o];
    out[(size_t)(row0 + row) * 5 + o] = s;
  }
}

static inline size_t alignup(size_t x) { return (x + 255) & ~(size_t)255; }

extern "C" void kernel_launch(void* const* d_in, const int* in_sizes, int n_in,
                              void* d_out, int out_size, void* d_ws, size_t ws_size,
                              hipStream_t stream) {
  (void)n_in; (void)out_size; (void)ws_size;
  const float* z   = (const float*)d_in[0];
  const int* edge  = (const int*)d_in[1];
  const int* batch = (const int*)d_in[2];
  const float* W0  = (const float*)d_in[4];
  const float* b0  = (const float*)d_in[5];
  const float* W1  = (const float*)d_in[6];
  const float* as1 = (const float*)d_in[7];
  const float* ad1 = (const float*)d_in[8];
  const float* bb1 = (const float*)d_in[9];
  const float* W2  = (const float*)d_in[10];
  const float* as2 = (const float*)d_in[11];
  const float* ad2 = (const float*)d_in[12];
  const float* bb2 = (const float*)d_in[13];
  const float* W3  = (const float*)d_in[14];
  const float* as3 = (const float*)d_in[15];
  const float* ad3 = (const float*)d_in[16];
  const float* bb3 = (const float*)d_in[17];
  const float* Wg  = (const float*)d_in[18];
  const float* bg  = (const float*)d_in[19];
  const float* Wf  = (const float*)d_in[20];
  const float* bfv = (const float*)d_in[21];
  float* out = (float*)d_out;

  const int E = in_sizes[1] / 2;
  const int N = in_sizes[2];
  const int* srcI = edge;
  const int* dstI = edge + E;

  char* w = (char*)d_ws;
  auto carve = [&](size_t bytes) { void* p = (void*)w; w += alignup(bytes); return p; };
  int* starts  = (int*)carve((size_t)GNUM * 4);
  int* cnt     = (int*)carve((size_t)N * 4);
  int* bucket  = (int*)carve((size_t)N * CAP * 4);
  float* A     = (float*)carve((size_t)GNUM * CH * 4);
  float* a_sA  = (float*)carve((size_t)N * 4 * 4);
  float* a_dA  = (float*)carve((size_t)N * 4 * 4);
  float* a_sB  = (float*)carve((size_t)N * 4 * 4);
  float* a_dB  = (float*)carve((size_t)N * 4 * 4);
  float* asg   = (float*)carve((size_t)GNUM * 4 * 4);
  float* adg   = (float*)carve((size_t)GNUM * 4 * 4);
  float* asp   = (float*)carve((size_t)POSMAX * 4 * 4);
  float* adp   = (float*)carve((size_t)POSMAX * 4 * 4);
  h16* W2T     = (h16*)carve((size_t)CH * CH * 2);
  h16* W3T     = (h16*)carve((size_t)CH * CH * 2);
  h16* WgT     = (h16*)carve((size_t)CH * FEAT * 2);
  h16* H16a    = (h16*)carve((size_t)N * CH * 2);
  h16* H16b    = (h16*)carve((size_t)N * CH * 2);

  int h1blocks = N / 8;                       // 2400
  int ebl = (E + 255) / 256;                  // 900

  hipLaunchKernelGGL(k_setup, dim3(576 + GNUM + POSMAX), dim3(256), 0, stream,
                     batch, cnt, starts, N, W2, W3, Wg, W2T, W3T, WgT, z, W0, b0, W1,
                     as1, ad1, A, asg, adg, asp, adp);
  hipLaunchKernelGGL(k_pre, dim3(h1blocks + ebl), dim3(256), 0, stream,
                     A, W1, batch, starts, asg, adg, asp, adp, H16a, a_sA, a_dA, N,
                     srcI, dstI, cnt, bucket, E, h1blocks);
  // layer 1 gather + layer-2 GEMM (a -> b)
  hipLaunchKernelGGL(k_fgg, dim3(N / 64), dim3(1024), 0, stream,
                     H16a, a_sA, a_dA, bb1, cnt, bucket, W2T, as2, ad2, H16b, a_sB, a_dB);
  // layer 2 gather + layer-3 GEMM (b -> a)
  hipLaunchKernelGGL(k_fgg, dim3(N / 64), dim3(1024), 0, stream,
                     H16b, a_sB, a_dB, bb2, cnt, bucket, W3T, as3, ad3, H16a, a_sA, a_dA);
  // layer 3 gather + head
  hipLaunchKernelGGL(k_fgh, dim3(N / 64), dim3(1024), 0, stream,
                     H16a, a_sA, a_dA, bb3, cnt, bucket, WgT, bg, Wf, bfv, out);
}

// Round 13
// 254.734 us; speedup vs baseline: 1.3197x; 1.3197x over previous
//
#include <hip/hip_runtime.h>
#include <hip/hip_fp16.h>

#define GNUM 128
#define HEADS 4
#define FEAT 64
#define CH 256      // HEADS*FEAT
#define LAT 256
#define SLOPE 0.2f
#define CAP 64      // max in-degree capacity (verified: max deg <= 64)
#define POSMAX 180  // one-hot position classes upper bound

typedef _Float16 h16;
typedef __attribute__((ext_vector_type(4))) _Float16 half4;
typedef __attribute__((ext_vector_type(8))) _Float16 half8;
typedef __attribute__((ext_vector_type(4))) float floatx4;

__device__ __forceinline__ float lrelu(float x) { return fmaxf(x, SLOPE * x); }

// ---- merged setup: [blocks 0..575] cnt=0 + starts + weight fp16 conversion;
//      [576..703] per-graph A row + graph logit table; [704..883] position logit table. ----
__global__ __launch_bounds__(256) void k_setup(const int* __restrict__ batch, int* __restrict__ cnt,
                                               int* __restrict__ starts, int n,
                                               const float* __restrict__ W2, const float* __restrict__ W3,
                                               const float* __restrict__ Wg, h16* __restrict__ W2T,
                                               h16* __restrict__ W3T, h16* __restrict__ WgT,
                                               const float* __restrict__ z, const float* __restrict__ W0,
                                               const float* __restrict__ b0, const float* __restrict__ W1,
                                               const float* __restrict__ as1, const float* __restrict__ ad1,
                                               float* __restrict__ A, float* __restrict__ asg,
                                               float* __restrict__ adg, float* __restrict__ asp,
                                               float* __restrict__ adp) {
  __shared__ float red[4][FEAT];
  __shared__ float xzs[FEAT];
  int bx = blockIdx.x, t = threadIdx.x;
  if (bx < 576) {
    int idx = bx * 256 + t;
    if (idx < n) {
      cnt[idx] = 0;
      int b = batch[idx];
      if (idx == 0 || batch[idx - 1] != b) starts[b] = idx;
    }
    if (idx < 65536) {
      int kb = idx >> 13, rem = idx & 8191, j = rem >> 8, nn = rem & 255;
      W2T[kb * 8192 + nn * 32 + j] = (h16)W2[(kb * 32 + j) * 256 + nn];
    } else if (idx < 131072) {
      int l = idx - 65536;
      int kb = l >> 13, rem = l & 8191, j = rem >> 8, nn = rem & 255;
      W3T[kb * 8192 + nn * 32 + j] = (h16)W3[(kb * 32 + j) * 256 + nn];
    } else {
      int l = idx - 131072;
      int kb = l >> 11, rem = l & 2047, j = rem >> 6, nn = rem & 63;
      WgT[kb * 2048 + nn * 32 + j] = (h16)Wg[(kb * 32 + j) * 64 + nn];
    }
  } else if (bx < 576 + GNUM) {
    int g = bx - 576;
    int f = t & 63, kq = t >> 6;
    float acc = 0.f;
    for (int k = kq * 64; k < kq * 64 + 64; ++k) acc += z[g * LAT + k] * W0[k * FEAT + f];
    red[kq][f] = acc;
    __syncthreads();
    if (kq == 0)
      xzs[f] = fmaxf(red[0][f] + red[1][f] + red[2][f] + red[3][f] + b0[f], 0.f);
    __syncthreads();
    float a2 = 0.f;
#pragma unroll 16
    for (int k = 0; k < FEAT; ++k) a2 += xzs[k] * W1[k * CH + t];
    A[g * CH + t] = a2;
    float ps = a2 * as1[t], pd = a2 * ad1[t];
#pragma unroll
    for (int sh = 1; sh < 64; sh <<= 1) {
      ps += __shfl_xor(ps, sh, 64);
      pd += __shfl_xor(pd, sh, 64);
    }
    if ((t & 63) == 0) {
      asg[g * 4 + (t >> 6)] = ps;
      adg[g * 4 + (t >> 6)] = pd;
    }
  } else {
    int p = bx - (576 + GNUM);
    float wv = W1[(size_t)(FEAT + p) * CH + t];
    float ps = wv * as1[t], pd = wv * ad1[t];
#pragma unroll
    for (int sh = 1; sh < 64; sh <<= 1) {
      ps += __shfl_xor(ps, sh, 64);
      pd += __shfl_xor(pd, sh, 64);
    }
    if ((t & 63) == 0) {
      asp[p * 4 + (t >> 6)] = ps;
      adp[p * 4 + (t >> 6)] = pd;
    }
  }
}

// ---- fused H1 materialization + logit tables [blocks 0..N/8) + edge scatter [rest]. ----
__global__ __launch_bounds__(256) void k_pre(const float* __restrict__ A, const float* __restrict__ W1,
                                             const int* __restrict__ batch, const int* __restrict__ starts,
                                             const float* __restrict__ asg, const float* __restrict__ adg,
                                             const float* __restrict__ asp, const float* __restrict__ adp,
                                             h16* __restrict__ H16, float* __restrict__ a_s,
                                             float* __restrict__ a_d, int n,
                                             const int* __restrict__ src, const int* __restrict__ dst,
                                             int* __restrict__ cnt, int* __restrict__ bucket, int e,
                                             int h1blocks) {
  int t = threadIdx.x;
  if ((int)blockIdx.x < h1blocks) {
    int row = blockIdx.x * 8 + (t >> 5);
    if (row < n) {
      int g = batch[row];
      int p = row - starts[g];
      int c0 = (t & 31) * 8;
      const float* ap = A + g * CH + c0;
      const float* wp = W1 + (size_t)(FEAT + p) * CH + c0;
      float4 a0 = *(const float4*)ap;
      float4 a1 = *(const float4*)(ap + 4);
      float4 w0v = *(const float4*)wp;
      float4 w1v = *(const float4*)(wp + 4);
      half8 o;
      o[0] = (h16)(a0.x + w0v.x); o[1] = (h16)(a0.y + w0v.y);
      o[2] = (h16)(a0.z + w0v.z); o[3] = (h16)(a0.w + w0v.w);
      o[4] = (h16)(a1.x + w1v.x); o[5] = (h16)(a1.y + w1v.y);
      o[6] = (h16)(a1.z + w1v.z); o[7] = (h16)(a1.w + w1v.w);
      *(half8*)(H16 + (size_t)row * CH + c0) = o;
    }
    int idx = blockIdx.x * 256 + t;
    if (idx < n * 4) {
      int nn = idx >> 2, h = idx & 3;
      int g2 = batch[nn], p2 = nn - starts[g2];
      a_s[idx] = asg[g2 * 4 + h] + asp[p2 * 4 + h];
      a_d[idx] = adg[g2 * 4 + h] + adp[p2 * 4 + h];
    }
  } else {
    int i = (blockIdx.x - h1blocks) * 256 + t;
    if (i < e) {
      int d = dst[i];
      int p = atomicAdd(&cnt[d], 1);
      if (p < CAP) bucket[d * CAP + p] = src[i];
    }
  }
}

// ======= fused layer v3.1: 256-thread block = 4 waves; 16 nodes/block (4 serial/wave,
//   straggler averaged over 4) at FULL occupancy (13.6 KB LDS -> 8 blocks/CU;
//   grid 1200). Phase B: 16x256 MFMA; wave wv = head strip wv; in-wave logits. =======
__global__ __launch_bounds__(256) void k_fgg(const h16* __restrict__ H16i, const float* __restrict__ a_si,
                                             const float* __restrict__ a_di, const float* __restrict__ bias,
                                             const int* __restrict__ cnt, const int* __restrict__ bucket,
                                             const h16* __restrict__ WT, const float* __restrict__ att_s,
                                             const float* __restrict__ att_d, h16* __restrict__ H16o,
                                             float* __restrict__ a_so, float* __restrict__ a_do_) {
  __shared__ __align__(16) h16 Xs[16 * 264];   // 8448 B (X tile, reused as H tile)
  __shared__ float wsh[4][CAP][4];             // 4096 B
  __shared__ int bsh[4][CAP];                  // 1024 B
  int t = threadIdx.x, wv = t >> 6, lane = t & 63;
  int quad = lane >> 4, l15 = lane & 15;
  int row0 = blockIdx.x * 16;
  int hh = lane >> 4, fo = lane * 4;
  // ---- Phase A: gather, 4 nodes per wave (R3-proven body, no barriers in loop) ----
  for (int i = 0; i < 4; ++i) {
    int n = row0 + wv * 4 + i;
    int c = min(cnt[n], CAP);
    bool valid = lane < c;
    int sc = valid ? bucket[n * CAP + lane] : n;
    if (valid) bsh[wv][lane] = sc;
    float4 ea4 = *(const float4*)(a_si + (size_t)sc * 4);
    float4 sn4 = *(const float4*)(a_si + (size_t)n * 4);
    float4 dn4 = *(const float4*)(a_di + (size_t)n * 4);
    float ea[4] = {ea4.x, ea4.y, ea4.z, ea4.w};
    float sn[4] = {sn4.x, sn4.y, sn4.z, sn4.w};
    float dn[4] = {dn4.x, dn4.y, dn4.z, dn4.w};
    float asf[4];
#pragma unroll
    for (int h = 0; h < 4; ++h) {
      float e = valid ? lrelu(ea[h] + dn[h]) : -1e30f;
      float es = lrelu(sn[h] + dn[h]);   // self loop logit
      float m = e;
#pragma unroll
      for (int sh = 1; sh < 64; sh <<= 1) m = fmaxf(m, __shfl_xor(m, sh, 64));
      m = fmaxf(m, es);
      float wgt = valid ? __expf(e - m) : 0.f;
      float ws = __expf(es - m);
      float s = wgt;
#pragma unroll
      for (int sh = 1; sh < 64; sh <<= 1) s += __shfl_xor(s, sh, 64);
      s += ws;
      float inv = 1.f / (s + 1e-16f);
      if (valid) wsh[wv][lane][h] = wgt * inv;
      asf[h] = ws * inv;
    }
    half4 hv = *(const half4*)(H16i + (size_t)n * CH + fo);
    float a_self = asf[hh];
    float acc0 = a_self * (float)hv[0];
    float acc1 = a_self * (float)hv[1];
    float acc2 = a_self * (float)hv[2];
    float acc3 = a_self * (float)hv[3];
#define GLD(k) (*(const half4*)(H16i + (size_t)bsh[wv][k] * CH + fo))
    half4 q0, q1, q2, q3, q4, q5, q6, q7;
    if (c > 0) q0 = GLD(0);
    if (c > 1) q1 = GLD(1);
    if (c > 2) q2 = GLD(2);
    if (c > 3) q3 = GLD(3);
    if (c > 4) q4 = GLD(4);
    if (c > 5) q5 = GLD(5);
    if (c > 6) q6 = GLD(6);
    if (c > 7) q7 = GLD(7);
    for (int j0 = 0; j0 < c; j0 += 8) {
#define STEP(K, QK)                                              \
      if (j0 + K < c) {                                          \
        float wj = wsh[wv][j0 + K][hh];                          \
        half4 hc = QK;                                           \
        if (j0 + K + 8 < c) QK = GLD(j0 + K + 8);                \
        acc0 += wj * (float)hc[0];                               \
        acc1 += wj * (float)hc[1];                               \
        acc2 += wj * (float)hc[2];                               \
        acc3 += wj * (float)hc[3];                               \
      }
      STEP(0, q0) STEP(1, q1) STEP(2, q2) STEP(3, q3)
      STEP(4, q4) STEP(5, q5) STEP(6, q6) STEP(7, q7)
#undef STEP
    }
#undef GLD
    float4 b4 = *(const float4*)(bias + fo);
    half4 o;
    o[0] = (h16)fmaxf(acc0 + b4.x, 0.f);
    o[1] = (h16)fmaxf(acc1 + b4.y, 0.f);
    o[2] = (h16)fmaxf(acc2 + b4.z, 0.f);
    o[3] = (h16)fmaxf(acc3 + b4.w, 0.f);
    *(half4*)&Xs[(wv * 4 + i) * 264 + fo] = o;
  }
  __syncthreads();   // X tile complete (couples only 4 waves)
  // ---- Phase B: 16x256 GEMM; wave wv = 64-col head strip wv ----
  floatx4 acc[4];
#pragma unroll
  for (int nt = 0; nt < 4; ++nt) acc[nt] = (floatx4){0.f, 0.f, 0.f, 0.f};
#pragma unroll
  for (int kb = 0; kb < 8; ++kb) {
    half8 af = *(const half8*)&Xs[l15 * 264 + kb * 32 + quad * 8];
    const h16* bp = WT + kb * 8192 + (wv * 64 + l15) * 32 + quad * 8;
    half8 b0 = *(const half8*)(bp + 0 * 512);
    half8 b1 = *(const half8*)(bp + 1 * 512);
    half8 b2 = *(const half8*)(bp + 2 * 512);
    half8 b3 = *(const half8*)(bp + 3 * 512);
    acc[0] = __builtin_amdgcn_mfma_f32_16x16x32_f16(af, b0, acc[0], 0, 0, 0);
    acc[1] = __builtin_amdgcn_mfma_f32_16x16x32_f16(af, b1, acc[1], 0, 0, 0);
    acc[2] = __builtin_amdgcn_mfma_f32_16x16x32_f16(af, b2, acc[2], 0, 0, 0);
    acc[3] = __builtin_amdgcn_mfma_f32_16x16x32_f16(af, b3, acc[3], 0, 0, 0);
  }
  // fused logits: strip wv == head wv; complete in-wave (R0-proven pattern)
  {
    float asv[4], adv[4];
#pragma unroll
    for (int nt = 0; nt < 4; ++nt) {
      asv[nt] = att_s[wv * FEAT + nt * 16 + l15];
      adv[nt] = att_d[wv * FEAT + nt * 16 + l15];
    }
#pragma unroll
    for (int r = 0; r < 4; ++r) {
      float ps = acc[0][r] * asv[0] + acc[1][r] * asv[1] +
                 acc[2][r] * asv[2] + acc[3][r] * asv[3];
      float pd = acc[0][r] * adv[0] + acc[1][r] * adv[1] +
                 acc[2][r] * adv[2] + acc[3][r] * adv[3];
#pragma unroll
      for (int sh = 1; sh < 16; sh <<= 1) {
        ps += __shfl_xor(ps, sh, 16);
        pd += __shfl_xor(pd, sh, 16);
      }
      if (l15 == 0) {
        int row = row0 + quad * 4 + r;
        a_so[(size_t)row * 4 + wv] = ps;
        a_do_[(size_t)row * 4 + wv] = pd;
      }
    }
  }
  __syncthreads();   // all Xs (af) reads done -> safe to overwrite with H tile
#pragma unroll
  for (int nt = 0; nt < 4; ++nt)
#pragma unroll
    for (int r = 0; r < 4; ++r)
      Xs[(quad * 4 + r) * 264 + wv * 64 + nt * 16 + l15] = (h16)acc[nt][r];
  __syncthreads();
  // H-tile to global (coalesced: 256 threads x 32 B = 16 rows x 512 B)
  {
    int row = t >> 4, seg = t & 15;
    const h16* srcr = &Xs[row * 264 + seg * 16];
    h16* dstr = H16o + (size_t)(row0 + row) * CH + seg * 16;
    *(half8*)(dstr + 0) = *(const half8*)(srcr + 0);
    *(half8*)(dstr + 8) = *(const half8*)(srcr + 8);
  }
}

// ======= fused last layer v3.1: gather (16 nodes, 4/wave) + head =======
__global__ __launch_bounds__(256) void k_fgh(const h16* __restrict__ H16i, const float* __restrict__ a_si,
                                             const float* __restrict__ a_di, const float* __restrict__ bias,
                                             const int* __restrict__ cnt, const int* __restrict__ bucket,
                                             const h16* __restrict__ WgT, const float* __restrict__ bg,
                                             const float* __restrict__ Wf, const float* __restrict__ bfv,
                                             float* __restrict__ out) {
  __shared__ __align__(16) h16 Xs[16 * 264];   // 8448 B
  __shared__ float wsh[4][CAP][4];             // 4096 B
  __shared__ int bsh[4][CAP];                  // 1024 B
  __shared__ float ytile[16][68];              // 4352 B
  __shared__ float WfS[FEAT * 5];              // 1280 B
  int t = threadIdx.x, wv = t >> 6, lane = t & 63;
  int quad = lane >> 4, l15 = lane & 15;
  int row0 = blockIdx.x * 16;
  int hh = lane >> 4, fo = lane * 4;
  for (int i = t; i < FEAT * 5; i += 256) WfS[i] = Wf[i];   // FIX R12: 320 > 256 needs strided loop
  // ---- Phase A: gather, 4 nodes per wave ----
  for (int i = 0; i < 4; ++i) {
    int n = row0 + wv * 4 + i;
    int c = min(cnt[n], CAP);
    bool valid = lane < c;
    int sc = valid ? bucket[n * CAP + lane] : n;
    if (valid) bsh[wv][lane] = sc;
    float4 ea4 = *(const float4*)(a_si + (size_t)sc * 4);
    float4 sn4 = *(const float4*)(a_si + (size_t)n * 4);
    float4 dn4 = *(const float4*)(a_di + (size_t)n * 4);
    float ea[4] = {ea4.x, ea4.y, ea4.z, ea4.w};
    float sn[4] = {sn4.x, sn4.y, sn4.z, sn4.w};
    float dn[4] = {dn4.x, dn4.y, dn4.z, dn4.w};
    float asf[4];
#pragma unroll
    for (int h = 0; h < 4; ++h) {
      float e = valid ? lrelu(ea[h] + dn[h]) : -1e30f;
      float es = lrelu(sn[h] + dn[h]);
      float m = e;
#pragma unroll
      for (int sh = 1; sh < 64; sh <<= 1) m = fmaxf(m, __shfl_xor(m, sh, 64));
      m = fmaxf(m, es);
      float wgt = valid ? __expf(e - m) : 0.f;
      float ws = __expf(es - m);
      float s = wgt;
#pragma unroll
      for (int sh = 1; sh < 64; sh <<= 1) s += __shfl_xor(s, sh, 64);
      s += ws;
      float inv = 1.f / (s + 1e-16f);
      if (valid) wsh[wv][lane][h] = wgt * inv;
      asf[h] = ws * inv;
    }
    half4 hv = *(const half4*)(H16i + (size_t)n * CH + fo);
    float a_self = asf[hh];
    float acc0 = a_self * (float)hv[0];
    float acc1 = a_self * (float)hv[1];
    float acc2 = a_self * (float)hv[2];
    float acc3 = a_self * (float)hv[3];
#define GLD(k) (*(const half4*)(H16i + (size_t)bsh[wv][k] * CH + fo))
    half4 q0, q1, q2, q3, q4, q5, q6, q7;
    if (c > 0) q0 = GLD(0);
    if (c > 1) q1 = GLD(1);
    if (c > 2) q2 = GLD(2);
    if (c > 3) q3 = GLD(3);
    if (c > 4) q4 = GLD(4);
    if (c > 5) q5 = GLD(5);
    if (c > 6) q6 = GLD(6);
    if (c > 7) q7 = GLD(7);
    for (int j0 = 0; j0 < c; j0 += 8) {
#define STEP(K, QK)                                              \
      if (j0 + K < c) {                                          \
        float wj = wsh[wv][j0 + K][hh];                          \
        half4 hc = QK;                                           \
        if (j0 + K + 8 < c) QK = GLD(j0 + K + 8);                \
        acc0 += wj * (float)hc[0];                               \
        acc1 += wj * (float)hc[1];                               \
        acc2 += wj * (float)hc[2];                               \
        acc3 += wj * (float)hc[3];                               \
      }
      STEP(0, q0) STEP(1, q1) STEP(2, q2) STEP(3, q3)
      STEP(4, q4) STEP(5, q5) STEP(6, q6) STEP(7, q7)
#undef STEP
    }
#undef GLD
    float4 b4 = *(const float4*)(bias + fo);
    half4 o;
    o[0] = (h16)fmaxf(acc0 + b4.x, 0.f);
    o[1] = (h16)fmaxf(acc1 + b4.y, 0.f);
    o[2] = (h16)fmaxf(acc2 + b4.z, 0.f);
    o[3] = (h16)fmaxf(acc3 + b4.w, 0.f);
    *(half4*)&Xs[(wv * 4 + i) * 264 + fo] = o;
  }
  __syncthreads();   // X tile + WfS complete
  // ---- Phase B: head GEMM 16x64; wave wv = 16-col strip ----
  floatx4 acc = (floatx4){0.f, 0.f, 0.f, 0.f};
#pragma unroll
  for (int kb = 0; kb < 8; ++kb) {
    half8 af = *(const half8*)&Xs[l15 * 264 + kb * 32 + quad * 8];
    half8 bf = *(const half8*)(WgT + kb * 2048 + (wv * 16 + l15) * 32 + quad * 8);
    acc = __builtin_amdgcn_mfma_f32_16x16x32_f16(af, bf, acc, 0, 0, 0);
  }
  {
    int col = wv * 16 + l15;
    float bgv = bg[col];
#pragma unroll
    for (int r = 0; r < 4; ++r)
      ytile[quad * 4 + r][col] = fmaxf(acc[r] + bgv, 0.f);
  }
  __syncthreads();
  if (t < 16 * 5) {
    int row = t / 5, o = t % 5;
    float s = bfv[o];
#pragma unroll
    for (int k = 0; k < FEAT; ++k) s += ytile[row][k] * WfS[k * 5 + o];
    out[(size_t)(row0 + row) * 5 + o] = s;
  }
}

static inline size_t alignup(size_t x) { return (x + 255) & ~(size_t)255; }

extern "C" void kernel_launch(void* const* d_in, const int* in_sizes, int n_in,
                              void* d_out, int out_size, void* d_ws, size_t ws_size,
                              hipStream_t stream) {
  (void)n_in; (void)out_size; (void)ws_size;
  const float* z   = (const float*)d_in[0];
  const int* edge  = (const int*)d_in[1];
  const int* batch = (const int*)d_in[2];
  const float* W0  = (const float*)d_in[4];
  const float* b0  = (const float*)d_in[5];
  const float* W1  = (const float*)d_in[6];
  const float* as1 = (const float*)d_in[7];
  const float* ad1 = (const float*)d_in[8];
  const float* bb1 = (const float*)d_in[9];
  const float* W2  = (const float*)d_in[10];
  const float* as2 = (const float*)d_in[11];
  const float* ad2 = (const float*)d_in[12];
  const float* bb2 = (const float*)d_in[13];
  const float* W3  = (const float*)d_in[14];
  const float* as3 = (const float*)d_in[15];
  const float* ad3 = (const float*)d_in[16];
  const float* bb3 = (const float*)d_in[17];
  const float* Wg  = (const float*)d_in[18];
  const float* bg  = (const float*)d_in[19];
  const float* Wf  = (const float*)d_in[20];
  const float* bfv = (const float*)d_in[21];
  float* out = (float*)d_out;

  const int E = in_sizes[1] / 2;
  const int N = in_sizes[2];
  const int* srcI = edge;
  const int* dstI = edge + E;

  char* w = (char*)d_ws;
  auto carve = [&](size_t bytes) { void* p = (void*)w; w += alignup(bytes); return p; };
  int* starts  = (int*)carve((size_t)GNUM * 4);
  int* cnt     = (int*)carve((size_t)N * 4);
  int* bucket  = (int*)carve((size_t)N * CAP * 4);
  float* A     = (float*)carve((size_t)GNUM * CH * 4);
  float* a_sA  = (float*)carve((size_t)N * 4 * 4);
  float* a_dA  = (float*)carve((size_t)N * 4 * 4);
  float* a_sB  = (float*)carve((size_t)N * 4 * 4);
  float* a_dB  = (float*)carve((size_t)N * 4 * 4);
  float* asg   = (float*)carve((size_t)GNUM * 4 * 4);
  float* adg   = (float*)carve((size_t)GNUM * 4 * 4);
  float* asp   = (float*)carve((size_t)POSMAX * 4 * 4);
  float* adp   = (float*)carve((size_t)POSMAX * 4 * 4);
  h16* W2T     = (h16*)carve((size_t)CH * CH * 2);
  h16* W3T     = (h16*)carve((size_t)CH * CH * 2);
  h16* WgT     = (h16*)carve((size_t)CH * FEAT * 2);
  h16* H16a    = (h16*)carve((size_t)N * CH * 2);
  h16* H16b    = (h16*)carve((size_t)N * CH * 2);

  int h1blocks = N / 8;                       // 2400
  int ebl = (E + 255) / 256;                  // 900

  hipLaunchKernelGGL(k_setup, dim3(576 + GNUM + POSMAX), dim3(256), 0, stream,
                     batch, cnt, starts, N, W2, W3, Wg, W2T, W3T, WgT, z, W0, b0, W1,
                     as1, ad1, A, asg, adg, asp, adp);
  hipLaunchKernelGGL(k_pre, dim3(h1blocks + ebl), dim3(256), 0, stream,
                     A, W1, batch, starts, asg, adg, asp, adp, H16a, a_sA, a_dA, N,
                     srcI, dstI, cnt, bucket, E, h1blocks);
  // layer 1 gather + layer-2 GEMM (a -> b)
  hipLaunchKernelGGL(k_fgg, dim3(N / 16), dim3(256), 0, stream,
                     H16a, a_sA, a_dA, bb1, cnt, bucket, W2T, as2, ad2, H16b, a_sB, a_dB);
  // layer 2 gather + layer-3 GEMM (b -> a)
  hipLaunchKernelGGL(k_fgg, dim3(N / 16), dim3(256), 0, stream,
                     H16b, a_sB, a_dB, bb2, cnt, bucket, W3T, as3, ad3, H16a, a_sA, a_dA);
  // layer 3 gather + head
  hipLaunchKernelGGL(k_fgh, dim3(N / 16), dim3(256), 0, stream,
                     H16a, a_sA, a_dA, bb3, cnt, bucket, WgT, bg, Wf, bfv, out);
}